// Round 1
// baseline (617.416 us; speedup 1.0000x reference)
//
#include <hip/hip_runtime.h>
#include <hip/hip_bf16.h>

typedef __attribute__((ext_vector_type(8))) short short8;
typedef __attribute__((ext_vector_type(4))) float f32x4;

__device__ inline unsigned short f2bf(float f) {
  __hip_bfloat16 h = __float2bfloat16(f);
  return *reinterpret_cast<unsigned short*>(&h);
}
__device__ inline float bf2f(unsigned short u) {
  union { unsigned u; float f; } v; v.u = ((unsigned)u) << 16;
  return v.f;
}

// C[M][N] = A[M][K] * B[N][K]^T.  A: f32 or bf16(ushort); B: f32 (converted); C: bf16 or f32.
template <bool A_BF16, bool OUT_F32>
__global__ __launch_bounds__(256, 2)
void gemm_bt(const void* __restrict__ Ap, const float* __restrict__ B,
             void* __restrict__ Cp, int M, int N, int K) {
  __shared__ __align__(16) unsigned short As[128][40];
  __shared__ __align__(16) unsigned short Bs[128][40];
  const int t = threadIdx.x;
  const int lane = t & 63, w = t >> 6;
  const int wr = w >> 1, wc = w & 1;
  const int r16 = lane & 15, kg = lane >> 4;
  const int bm = blockIdx.x, bn = blockIdx.y;
  const int srow = t >> 1, skc = (t & 1) * 16;

  f32x4 acc[4][4] = {};

  const float* Af = (const float*)Ap;
  const unsigned short* Ah = (const unsigned short*)Ap;
  const size_t arow = (size_t)(bm * 128 + srow) * K;
  const size_t brow = (size_t)(bn * 128 + srow) * K;

  for (int k0 = 0; k0 < K; k0 += 32) {
    unsigned short abuf[16], bbuf[16];
    if (A_BF16) {
      *(short8*)&abuf[0] = *(const short8*)(Ah + arow + k0 + skc);
      *(short8*)&abuf[8] = *(const short8*)(Ah + arow + k0 + skc + 8);
    } else {
      const float* ap = Af + arow + k0 + skc;
#pragma unroll
      for (int i = 0; i < 4; ++i) {
        float4 v = *(const float4*)(ap + i * 4);
        abuf[i * 4 + 0] = f2bf(v.x); abuf[i * 4 + 1] = f2bf(v.y);
        abuf[i * 4 + 2] = f2bf(v.z); abuf[i * 4 + 3] = f2bf(v.w);
      }
    }
    {
      const float* bp = B + brow + k0 + skc;
#pragma unroll
      for (int i = 0; i < 4; ++i) {
        float4 v = *(const float4*)(bp + i * 4);
        bbuf[i * 4 + 0] = f2bf(v.x); bbuf[i * 4 + 1] = f2bf(v.y);
        bbuf[i * 4 + 2] = f2bf(v.z); bbuf[i * 4 + 3] = f2bf(v.w);
      }
    }
    __syncthreads();  // prior iteration's LDS reads complete
    *(short8*)&As[srow][skc]     = *(short8*)&abuf[0];
    *(short8*)&As[srow][skc + 8] = *(short8*)&abuf[8];
    *(short8*)&Bs[srow][skc]     = *(short8*)&bbuf[0];
    *(short8*)&Bs[srow][skc + 8] = *(short8*)&bbuf[8];
    __syncthreads();  // staging complete

    short8 a[4], b[4];
#pragma unroll
    for (int m = 0; m < 4; ++m) a[m] = *(const short8*)&As[wr * 64 + m * 16 + r16][kg * 8];
#pragma unroll
    for (int n = 0; n < 4; ++n) b[n] = *(const short8*)&Bs[wc * 64 + n * 16 + r16][kg * 8];
#pragma unroll
    for (int m = 0; m < 4; ++m)
#pragma unroll
      for (int n = 0; n < 4; ++n)
        acc[m][n] = __builtin_amdgcn_mfma_f32_16x16x32_bf16(a[m], b[n], acc[m][n], 0, 0, 0);
  }

#pragma unroll
  for (int m = 0; m < 4; ++m) {
#pragma unroll
    for (int n = 0; n < 4; ++n) {
#pragma unroll
      for (int j = 0; j < 4; ++j) {
        int row = bm * 128 + wr * 64 + m * 16 + kg * 4 + j;
        int col = bn * 128 + wc * 64 + n * 16 + r16;
        if (OUT_F32) ((float*)Cp)[(size_t)row * N + col] = acc[m][n][j];
        else ((unsigned short*)Cp)[(size_t)row * N + col] = f2bf(acc[m][n][j]);
      }
    }
  }
}

// RoPE for q heads (with 1/sqrt(hs) scale) and k groups; scatter to per-head layouts.
// Q[h][t][d] (32 heads), K[g][t][d] (8 groups)
__global__ void rope_qk(const unsigned short* __restrict__ qkv,
                        const float* __restrict__ cosb, const float* __restrict__ sinb,
                        unsigned short* __restrict__ Q, unsigned short* __restrict__ K) {
  int pair = blockIdx.x * 4 + (threadIdx.x >> 6);
  int l = threadIdx.x & 63;
  int t = pair / 40, slot = pair - t * 40;
  const unsigned short* src;
  unsigned short* dst;
  float scale;
  if (slot < 32) {
    int g = slot >> 2, j = slot & 3;
    src = qkv + (size_t)t * 6144 + g * 768 + j * 128;
    dst = Q + ((size_t)slot * 2048 + t) * 128;
    scale = 0.08838834764831845f;  // 1/sqrt(128)
  } else {
    int g = slot - 32;
    src = qkv + (size_t)t * 6144 + g * 768 + 512;
    dst = K + ((size_t)g * 2048 + t) * 128;
    scale = 1.0f;
  }
  float x1 = bf2f(src[l]), x2 = bf2f(src[64 + l]);
  float c1 = cosb[t * 128 + l], s1 = sinb[t * 128 + l];
  float c2 = cosb[t * 128 + 64 + l], s2 = sinb[t * 128 + 64 + l];
  dst[l]      = f2bf((x1 * c1 - x2 * s1) * scale);
  dst[64 + l] = f2bf((x2 * c2 + x1 * s2) * scale);
}

// Vt[g][d][t] = qkv[t][g*768+640+d]
__global__ void transpose_v(const unsigned short* __restrict__ qkv,
                            unsigned short* __restrict__ Vt) {
  __shared__ __align__(16) unsigned short tile[64][136];
  int g = blockIdx.y, t0 = blockIdx.x * 64;
  int th = threadIdx.x;
  int r = th >> 2, c0 = (th & 3) * 32;
  const unsigned short* src = qkv + (size_t)(t0 + r) * 6144 + g * 768 + 640 + c0;
#pragma unroll
  for (int i = 0; i < 4; ++i)
    *(short8*)&tile[r][c0 + i * 8] = *(const short8*)(src + i * 8);
  __syncthreads();
  int d = th >> 1, tc = (th & 1) * 32;
  unsigned short* dst = Vt + (size_t)(g * 128 + d) * 2048 + t0 + tc;
#pragma unroll
  for (int j = 0; j < 32; ++j) dst[j] = tile[tc + j][d];
}

// Flash attention, causal. 1 block = 1 head x 64 q-rows (4 waves x 16 rows). KV tile = 64.
__global__ __launch_bounds__(256, 2)
void flash_attn(const unsigned short* __restrict__ Q, const unsigned short* __restrict__ K,
                const unsigned short* __restrict__ Vt, unsigned short* __restrict__ Y) {
  __shared__ __align__(16) unsigned short Ksm[64 * 128];   // [kv][d], XOR-swizzled
  __shared__ __align__(16) unsigned short Vsm[128 * 64];   // [d][kv], XOR-swizzled
  __shared__ __align__(16) unsigned short Psm[4][16][72];  // per-wave P, padded

  const int h = blockIdx.y, g = h >> 2;
  const int q0 = blockIdx.x * 64;
  const int t = threadIdx.x, lane = t & 63, w = t >> 6;
  const int r16 = lane & 15, kg = lane >> 4;

  short8 qf[4];
  const unsigned short* qrow = Q + ((size_t)h * 2048 + q0 + w * 16 + r16) * 128;
#pragma unroll
  for (int kk = 0; kk < 4; ++kk) qf[kk] = *(const short8*)(qrow + kk * 32 + kg * 8);

  const unsigned short* Kg = K + (size_t)g * 2048 * 128;
  const unsigned short* Vg = Vt + (size_t)g * 128 * 2048;

  f32x4 o[8] = {};
  float mrow[4] = {-1e30f, -1e30f, -1e30f, -1e30f};
  float lrow[4] = {0.f, 0.f, 0.f, 0.f};

  const int kvend = q0 + 64;
  for (int kv0 = 0; kv0 < kvend; kv0 += 64) {
    short8 kreg[4], vreg[4];
#pragma unroll
    for (int p = 0; p < 4; ++p) {
      int o16 = p * 256 + t;
      int kr = o16 >> 4, ks = o16 & 15;
      kreg[p] = *(const short8*)(Kg + (size_t)(kv0 + kr) * 128 + ks * 8);
      int vd = o16 >> 3, vs = o16 & 7;
      vreg[p] = *(const short8*)(Vg + (size_t)vd * 2048 + kv0 + vs * 8);
    }
    __syncthreads();
#pragma unroll
    for (int p = 0; p < 4; ++p) {
      int o16 = p * 256 + t;
      int kr = o16 >> 4, ks = o16 & 15;
      *(short8*)__builtin_assume_aligned(&Ksm[kr * 128 + ((ks * 8) ^ ((kr & 7) << 3))], 16) = kreg[p];
      int vd = o16 >> 3, vs = o16 & 7;
      *(short8*)__builtin_assume_aligned(&Vsm[vd * 64 + ((vs * 8) ^ ((vd & 7) << 3))], 16) = vreg[p];
    }
    __syncthreads();

    // S = Q K^T  (rows: q-local = kg*4+j, cols: kv-local = n*16+r16)
    f32x4 s[4] = {};
#pragma unroll
    for (int n = 0; n < 4; ++n) {
      int kvcol = n * 16 + r16;
#pragma unroll
      for (int kk = 0; kk < 4; ++kk) {
        short8 kf = *(const short8*)__builtin_assume_aligned(
            &Ksm[kvcol * 128 + ((kk * 32 + kg * 8) ^ ((kvcol & 7) << 3))], 16);
        s[n] = __builtin_amdgcn_mfma_f32_16x16x32_bf16(qf[kk], kf, s[n], 0, 0, 0);
      }
    }

    float rmax[4] = {-1e30f, -1e30f, -1e30f, -1e30f};
    const int qglob = q0 + w * 16 + kg * 4;
#pragma unroll
    for (int n = 0; n < 4; ++n) {
      int kvg = kv0 + n * 16 + r16;
#pragma unroll
      for (int j = 0; j < 4; ++j) {
        if (kvg > qglob + j) s[n][j] = -1e30f;
        rmax[j] = fmaxf(rmax[j], s[n][j]);
      }
    }
#pragma unroll
    for (int j = 0; j < 4; ++j)
#pragma unroll
      for (int off = 1; off < 16; off <<= 1)
        rmax[j] = fmaxf(rmax[j], __shfl_xor(rmax[j], off));

    float fac[4], rsum[4];
#pragma unroll
    for (int j = 0; j < 4; ++j) {
      float mnew = fmaxf(mrow[j], rmax[j]);
      fac[j] = __expf(mrow[j] - mnew);
      mrow[j] = mnew;
      rsum[j] = 0.f;
    }
#pragma unroll
    for (int n = 0; n < 4; ++n)
#pragma unroll
      for (int j = 0; j < 4; ++j) {
        float p = __expf(s[n][j] - mrow[j]);
        rsum[j] += p;
        Psm[w][kg * 4 + j][n * 16 + r16] = f2bf(p);
      }
#pragma unroll
    for (int j = 0; j < 4; ++j) {
#pragma unroll
      for (int off = 1; off < 16; off <<= 1) rsum[j] += __shfl_xor(rsum[j], off);
      lrow[j] = lrow[j] * fac[j] + rsum[j];
    }
#pragma unroll
    for (int f = 0; f < 8; ++f)
#pragma unroll
      for (int j = 0; j < 4; ++j) o[f][j] *= fac[j];

    // O += P V
#pragma unroll
    for (int kk = 0; kk < 2; ++kk) {
      short8 pf = *(const short8*)__builtin_assume_aligned(&Psm[w][r16][kk * 32 + kg * 8], 16);
#pragma unroll
      for (int f = 0; f < 8; ++f) {
        int d = f * 16 + r16;
        short8 vf = *(const short8*)__builtin_assume_aligned(
            &Vsm[d * 64 + ((kk * 32 + kg * 8) ^ ((d & 7) << 3))], 16);
        o[f] = __builtin_amdgcn_mfma_f32_16x16x32_bf16(pf, vf, o[f], 0, 0, 0);
      }
    }
  }

#pragma unroll
  for (int j = 0; j < 4; ++j) {
    float inv = 1.f / lrow[j];
    int row = q0 + w * 16 + kg * 4 + j;
    unsigned short* yr = Y + (size_t)row * 4096 + h * 128;
#pragma unroll
    for (int f = 0; f < 8; ++f) yr[f * 16 + r16] = f2bf(o[f][j] * inv);
  }
}

extern "C" void kernel_launch(void* const* d_in, const int* in_sizes, int n_in,
                              void* d_out, int out_size, void* d_ws, size_t ws_size,
                              hipStream_t stream) {
  const float* x      = (const float*)d_in[0];
  const float* cosb   = (const float*)d_in[1];
  const float* sinb   = (const float*)d_in[2];
  const float* w_attn = (const float*)d_in[3];
  const float* w_proj = (const float*)d_in[4];
  float* out = (float*)d_out;

  char* ws = (char*)d_ws;
  unsigned short* qkv = (unsigned short*)ws;                    // 2048*6144 bf16 = 24 MiB
  unsigned short* Qb  = (unsigned short*)(ws + 25165824);       // 32*2048*128  = 16 MiB
  unsigned short* Kb  = (unsigned short*)(ws + 41943040);       //  8*2048*128  =  4 MiB
  unsigned short* Vt  = (unsigned short*)(ws + 46137344);       //  8*128*2048  =  4 MiB
  unsigned short* Yb  = (unsigned short*)(ws + 50331648);       // 2048*4096    = 16 MiB

  gemm_bt<false, false><<<dim3(16, 48), 256, 0, stream>>>(x, w_attn, qkv, 2048, 6144, 4096);
  rope_qk<<<20480, 256, 0, stream>>>(qkv, cosb, sinb, Qb, Kb);
  transpose_v<<<dim3(32, 8), 256, 0, stream>>>(qkv, Vt);
  flash_attn<<<dim3(32, 32), 256, 0, stream>>>(Qb, Kb, Vt, Yb);
  gemm_bt<true, true><<<dim3(16, 32), 256, 0, stream>>>(Yb, w_proj, out, 2048, 4096, 4096);
}

// Round 2
// 436.389 us; speedup vs baseline: 1.4148x; 1.4148x over previous
//
#include <hip/hip_runtime.h>
#include <hip/hip_bf16.h>

typedef __attribute__((ext_vector_type(8))) short short8;
typedef __attribute__((ext_vector_type(4))) float f32x4;

__device__ inline unsigned short f2bf(float f) {
  __hip_bfloat16 h = __float2bfloat16(f);
  return *reinterpret_cast<unsigned short*>(&h);
}
__device__ inline float bf2f(unsigned short u) {
  union { unsigned u; float f; } v; v.u = ((unsigned)u) << 16;
  return v.f;
}

#define GLOAD_LDS16(g, l)                                          \
  __builtin_amdgcn_global_load_lds(                                \
      (const __attribute__((address_space(1))) void*)(g),          \
      (__attribute__((address_space(3))) void*)(l), 16, 0, 0)

// ---------------- f32 -> bf16 bulk convert (8 elems/thread) ----------------
__global__ void f32_to_bf16(const float* __restrict__ in,
                            unsigned short* __restrict__ out, int n8) {
  int i = blockIdx.x * 256 + threadIdx.x;
  if (i >= n8) return;
  const float4* p = (const float4*)in + (size_t)i * 2;
  float4 a = p[0], b = p[1];
  short8 v;
  v[0] = f2bf(a.x); v[1] = f2bf(a.y); v[2] = f2bf(a.z); v[3] = f2bf(a.w);
  v[4] = f2bf(b.x); v[5] = f2bf(b.y); v[6] = f2bf(b.z); v[7] = f2bf(b.w);
  *((short8*)out + i) = v;
}

// ---- m97-structure GEMM: C[M][N] = A[M][K] * B[N][K]^T, bf16 in, 128^2 tile ----
template <bool OUT_F32>
__global__ __launch_bounds__(256, 3)
void gemm_bt_bf16(const unsigned short* __restrict__ A,
                  const unsigned short* __restrict__ B,
                  void* __restrict__ Cp, int M, int N, int K) {
  __shared__ __align__(16) unsigned short As[128 * 32];
  __shared__ __align__(16) unsigned short Bs[128 * 32];
  const int t = threadIdx.x;
  const int lane = t & 63, w = t >> 6;
  const int wr = w >> 1, wc = w & 1;
  const int r16 = lane & 15, kg = lane >> 4;
  const int bm = blockIdx.x, bn = blockIdx.y;

  // staging: issue i covers rows i*64..i*64+63; wave w covers 16 rows; lane -> 8 cols
  const int srow = w * 16 + (lane >> 2);
  const int scol = (lane & 3) * 8;

  const unsigned short* Ag = A + (size_t)(bm * 128) * K;
  const unsigned short* Bg = B + (size_t)(bn * 128) * K;

  f32x4 acc[4][4] = {};

  for (int k0 = 0; k0 < K; k0 += 32) {
    __syncthreads();  // all waves done reading LDS from previous step
#pragma unroll
    for (int i = 0; i < 2; ++i) {
      GLOAD_LDS16(Ag + (size_t)(i * 64 + srow) * K + k0 + scol,
                  As + i * 2048 + w * 512);
      GLOAD_LDS16(Bg + (size_t)(i * 64 + srow) * K + k0 + scol,
                  Bs + i * 2048 + w * 512);
    }
    __syncthreads();  // staging complete (compiler drains vmcnt before barrier)

    short8 a[4], b[4];
#pragma unroll
    for (int m = 0; m < 4; ++m)
      a[m] = *(const short8*)&As[(wr * 64 + m * 16 + r16) * 32 + kg * 8];
#pragma unroll
    for (int n = 0; n < 4; ++n)
      b[n] = *(const short8*)&Bs[(wc * 64 + n * 16 + r16) * 32 + kg * 8];
#pragma unroll
    for (int m = 0; m < 4; ++m)
#pragma unroll
      for (int n = 0; n < 4; ++n)
        acc[m][n] = __builtin_amdgcn_mfma_f32_16x16x32_bf16(a[m], b[n], acc[m][n], 0, 0, 0);
  }

#pragma unroll
  for (int m = 0; m < 4; ++m) {
#pragma unroll
    for (int n = 0; n < 4; ++n) {
#pragma unroll
      for (int j = 0; j < 4; ++j) {
        int row = bm * 128 + wr * 64 + m * 16 + kg * 4 + j;
        int col = bn * 128 + wc * 64 + n * 16 + r16;
        if (OUT_F32) ((float*)Cp)[(size_t)row * N + col] = acc[m][n][j];
        else ((unsigned short*)Cp)[(size_t)row * N + col] = f2bf(acc[m][n][j]);
      }
    }
  }
}

// ---------------- RoPE for Q (with 1/sqrt(hs)) and K; scatter ----------------
__global__ void rope_qk(const unsigned short* __restrict__ qkv,
                        const float* __restrict__ cosb, const float* __restrict__ sinb,
                        unsigned short* __restrict__ Q, unsigned short* __restrict__ K) {
  int pair = blockIdx.x * 4 + (threadIdx.x >> 6);
  int l = threadIdx.x & 63;
  int t = pair / 40, slot = pair - t * 40;
  const unsigned short* src;
  unsigned short* dst;
  float scale;
  if (slot < 32) {
    int g = slot >> 2, j = slot & 3;
    src = qkv + (size_t)t * 6144 + g * 768 + j * 128;
    dst = Q + ((size_t)slot * 2048 + t) * 128;
    scale = 0.08838834764831845f;  // 1/sqrt(128)
  } else {
    int g = slot - 32;
    src = qkv + (size_t)t * 6144 + g * 768 + 512;
    dst = K + ((size_t)g * 2048 + t) * 128;
    scale = 1.0f;
  }
  float x1 = bf2f(src[l]), x2 = bf2f(src[64 + l]);
  float c1 = cosb[t * 128 + l], s1 = sinb[t * 128 + l];
  float c2 = cosb[t * 128 + 64 + l], s2 = sinb[t * 128 + 64 + l];
  dst[l]      = f2bf((x1 * c1 - x2 * s1) * scale);
  dst[64 + l] = f2bf((x2 * c2 + x1 * s2) * scale);
}

// ---------------- Vt[g][d][t] = qkv[t][g*768+640+d] ----------------
__global__ void transpose_v(const unsigned short* __restrict__ qkv,
                            unsigned short* __restrict__ Vt) {
  __shared__ __align__(16) unsigned short tile[64][136];
  int g = blockIdx.y, t0 = blockIdx.x * 64;
  int th = threadIdx.x;
  int r = th >> 2, c0 = (th & 3) * 32;
  const unsigned short* src = qkv + (size_t)(t0 + r) * 6144 + g * 768 + 640 + c0;
#pragma unroll
  for (int i = 0; i < 4; ++i)
    *(short8*)&tile[r][c0 + i * 8] = *(const short8*)(src + i * 8);
  __syncthreads();
  int d = th >> 1, tc = (th & 1) * 32;
  unsigned short* dst = Vt + (size_t)(g * 128 + d) * 2048 + t0 + tc;
#pragma unroll
  for (int j = 0; j < 32; ++j) dst[j] = tile[tc + j][d];
}

// ---------------- Flash attention, causal ----------------
__global__ __launch_bounds__(256, 2)
void flash_attn(const unsigned short* __restrict__ Q, const unsigned short* __restrict__ K,
                const unsigned short* __restrict__ Vt, unsigned short* __restrict__ Y) {
  __shared__ __align__(16) unsigned short Ksm[64 * 128];   // [kv][d], XOR-swizzled
  __shared__ __align__(16) unsigned short Vsm[128 * 64];   // [d][kv], XOR-swizzled
  __shared__ __align__(16) unsigned short Psm[4][16][72];  // per-wave P, padded

  const int h = blockIdx.y, g = h >> 2;
  const int q0 = (gridDim.x - 1 - blockIdx.x) * 64;  // heavy tiles dispatch first
  const int t = threadIdx.x, lane = t & 63, w = t >> 6;
  const int r16 = lane & 15, kg = lane >> 4;

  short8 qf[4];
  const unsigned short* qrow = Q + ((size_t)h * 2048 + q0 + w * 16 + r16) * 128;
#pragma unroll
  for (int kk = 0; kk < 4; ++kk) qf[kk] = *(const short8*)(qrow + kk * 32 + kg * 8);

  const unsigned short* Kg = K + (size_t)g * 2048 * 128;
  const unsigned short* Vg = Vt + (size_t)g * 128 * 2048;

  f32x4 o[8] = {};
  float mrow[4] = {-1e30f, -1e30f, -1e30f, -1e30f};
  float lrow[4] = {0.f, 0.f, 0.f, 0.f};

  const int kvend = q0 + 64;
  for (int kv0 = 0; kv0 < kvend; kv0 += 64) {
    short8 kreg[4], vreg[4];
#pragma unroll
    for (int p = 0; p < 4; ++p) {
      int o16 = p * 256 + t;
      int kr = o16 >> 4, ks = o16 & 15;
      kreg[p] = *(const short8*)(Kg + (size_t)(kv0 + kr) * 128 + ks * 8);
      int vd = o16 >> 3, vs = o16 & 7;
      vreg[p] = *(const short8*)(Vg + (size_t)vd * 2048 + kv0 + vs * 8);
    }
    __syncthreads();
#pragma unroll
    for (int p = 0; p < 4; ++p) {
      int o16 = p * 256 + t;
      int kr = o16 >> 4, ks = o16 & 15;
      *(short8*)__builtin_assume_aligned(&Ksm[kr * 128 + ((ks * 8) ^ ((kr & 7) << 3))], 16) = kreg[p];
      int vd = o16 >> 3, vs = o16 & 7;
      *(short8*)__builtin_assume_aligned(&Vsm[vd * 64 + ((vs * 8) ^ ((vd & 7) << 3))], 16) = vreg[p];
    }
    __syncthreads();

    f32x4 s[4] = {};
#pragma unroll
    for (int n = 0; n < 4; ++n) {
      int kvcol = n * 16 + r16;
#pragma unroll
      for (int kk = 0; kk < 4; ++kk) {
        short8 kf = *(const short8*)__builtin_assume_aligned(
            &Ksm[kvcol * 128 + ((kk * 32 + kg * 8) ^ ((kvcol & 7) << 3))], 16);
        s[n] = __builtin_amdgcn_mfma_f32_16x16x32_bf16(qf[kk], kf, s[n], 0, 0, 0);
      }
    }

    float rmax[4] = {-1e30f, -1e30f, -1e30f, -1e30f};
    const int qglob = q0 + w * 16 + kg * 4;
#pragma unroll
    for (int n = 0; n < 4; ++n) {
      int kvg = kv0 + n * 16 + r16;
#pragma unroll
      for (int j = 0; j < 4; ++j) {
        if (kvg > qglob + j) s[n][j] = -1e30f;
        rmax[j] = fmaxf(rmax[j], s[n][j]);
      }
    }
#pragma unroll
    for (int j = 0; j < 4; ++j)
#pragma unroll
      for (int off = 1; off < 16; off <<= 1)
        rmax[j] = fmaxf(rmax[j], __shfl_xor(rmax[j], off));

    float fac[4], rsum[4];
#pragma unroll
    for (int j = 0; j < 4; ++j) {
      float mnew = fmaxf(mrow[j], rmax[j]);
      fac[j] = __expf(mrow[j] - mnew);
      mrow[j] = mnew;
      rsum[j] = 0.f;
    }
#pragma unroll
    for (int n = 0; n < 4; ++n)
#pragma unroll
      for (int j = 0; j < 4; ++j) {
        float p = __expf(s[n][j] - mrow[j]);
        rsum[j] += p;
        Psm[w][kg * 4 + j][n * 16 + r16] = f2bf(p);
      }
#pragma unroll
    for (int j = 0; j < 4; ++j) {
#pragma unroll
      for (int off = 1; off < 16; off <<= 1) rsum[j] += __shfl_xor(rsum[j], off);
      lrow[j] = lrow[j] * fac[j] + rsum[j];
    }
#pragma unroll
    for (int f = 0; f < 8; ++f)
#pragma unroll
      for (int j = 0; j < 4; ++j) o[f][j] *= fac[j];

#pragma unroll
    for (int kk = 0; kk < 2; ++kk) {
      short8 pf = *(const short8*)__builtin_assume_aligned(&Psm[w][r16][kk * 32 + kg * 8], 16);
#pragma unroll
      for (int f = 0; f < 8; ++f) {
        int d = f * 16 + r16;
        short8 vf = *(const short8*)__builtin_assume_aligned(
            &Vsm[d * 64 + ((kk * 32 + kg * 8) ^ ((d & 7) << 3))], 16);
        o[f] = __builtin_amdgcn_mfma_f32_16x16x32_bf16(pf, vf, o[f], 0, 0, 0);
      }
    }
  }

#pragma unroll
  for (int j = 0; j < 4; ++j) {
    float inv = 1.f / lrow[j];
    int row = q0 + w * 16 + kg * 4 + j;
    unsigned short* yr = Y + (size_t)row * 4096 + h * 128;
#pragma unroll
    for (int f = 0; f < 8; ++f) yr[f * 16 + r16] = f2bf(o[f][j] * inv);
  }
}

extern "C" void kernel_launch(void* const* d_in, const int* in_sizes, int n_in,
                              void* d_out, int out_size, void* d_ws, size_t ws_size,
                              hipStream_t stream) {
  const float* x      = (const float*)d_in[0];
  const float* cosb   = (const float*)d_in[1];
  const float* sinb   = (const float*)d_in[2];
  const float* w_attn = (const float*)d_in[3];
  const float* w_proj = (const float*)d_in[4];
  float* out = (float*)d_out;

  // Workspace layout with lifetime-based aliasing (peak 88 MiB):
  //  [0,16M):   Xb (x bf16)            — dead after gemm1; Wp overlays [0,32M)
  //  [16M,64M): Wa (w_attn bf16)       — dead after gemm1; Qb/Kb/Vt overlay
  //  [64M,88M): qkv bf16               — dead after rope+transpose; Yb overlays
  char* ws = (char*)d_ws;
  const size_t MB = 1024 * 1024;
  unsigned short* Xb  = (unsigned short*)(ws);
  unsigned short* Wa  = (unsigned short*)(ws + 16 * MB);
  unsigned short* Wp  = (unsigned short*)(ws);            // after gemm1
  unsigned short* Qb  = (unsigned short*)(ws + 32 * MB);  // after gemm1
  unsigned short* Kb  = (unsigned short*)(ws + 48 * MB);  // after gemm1
  unsigned short* Vt  = (unsigned short*)(ws + 52 * MB);  // after gemm1
  unsigned short* qkv = (unsigned short*)(ws + 64 * MB);
  unsigned short* Yb  = (unsigned short*)(ws + 64 * MB);  // after rope+transpose

  f32_to_bf16<<<4096, 256, 0, stream>>>(x, Xb, 2048 * 4096 / 8);
  f32_to_bf16<<<12288, 256, 0, stream>>>(w_attn, Wa, 6144 * 4096 / 8);
  gemm_bt_bf16<false><<<dim3(16, 48), 256, 0, stream>>>(Xb, Wa, qkv, 2048, 6144, 4096);
  rope_qk<<<20480, 256, 0, stream>>>(qkv, cosb, sinb, Qb, Kb);
  transpose_v<<<dim3(32, 8), 256, 0, stream>>>(qkv, Vt);
  f32_to_bf16<<<8192, 256, 0, stream>>>(w_proj, Wp, 4096 * 4096 / 8);
  flash_attn<<<dim3(32, 32), 256, 0, stream>>>(Qb, Kb, Vt, Yb);
  gemm_bt_bf16<true><<<dim3(16, 32), 256, 0, stream>>>(Yb, Wp, out, 2048, 4096, 4096);
}